// Round 2
// baseline (458.153 us; speedup 1.0000x reference)
//
#include <hip/hip_runtime.h>

namespace {

constexpr int U = 128;
constexpr float INV_SQRT3 = 0.57735026918962576f;  // 1/sqrt(3)
constexpr float INV_SQRT2 = 0.70710678118654752f;  // 1/sqrt(2)

// One thread handles 4 consecutive channels (u4 = u/4 in [0,32)).
// Every global access is a 16-byte float4 at 16B-aligned addresses:
//   x1 row (2048B): s0 = f4[u4]; s1 = f4[32+3u4 .. 34+3u4]
//   out row (5632B = 352 f4): o0 @ f4 u4, o1 @ 32+3u4, o2 @ 128+3u4,
//                             o3 @ 224+u4, o4 @ 256+3u4
__global__ __launch_bounds__(256) void tp_kernel(
    const float* __restrict__ x1, const float* __restrict__ x2,
    const float* __restrict__ w, float* __restrict__ out, int nrows) {
  const int t = blockIdx.x * blockDim.x + threadIdx.x;
  const int b = t >> 5;         // batch row (32 threads per row)
  const int u4 = t & 31;        // 4-channel group
  if (b >= nrows) return;

  const float4* x1r = reinterpret_cast<const float4*>(x1) + (size_t)b * 128;
  const float4 s0 = x1r[u4];
  const float4 sA = x1r[32 + 3 * u4];   // c0.x c0.y c0.z c1.x
  const float4 sB = x1r[33 + 3 * u4];   // c1.y c1.z c2.x c2.y
  const float4 sC = x1r[34 + 3 * u4];   // c2.z c3.x c3.y c3.z

  const float4 y = reinterpret_cast<const float4*>(x2)[b];  // y0, y1[0..2]

  const float4* wv = reinterpret_cast<const float4*>(w);
  const float4 w0 = wv[u4];
  const float4 w1 = wv[32 + u4];
  const float4 w2 = wv[64 + u4];
  const float4 w3 = wv[96 + u4];
  const float4 w4 = wv[128 + u4];

  float4* orow = reinterpret_cast<float4*>(out) + (size_t)b * 352;

  // o0[c] = w0[c] * s0[c] * y0
  orow[u4] = make_float4(w0.x * s0.x * y.x, w0.y * s0.y * y.x,
                         w0.z * s0.z * y.x, w0.w * s0.w * y.x);

  // o1[c,i] = w1[c] * s0[c] * y1[i]   (channel-major, 3 per channel)
  const float t10 = w1.x * s0.x, t11 = w1.y * s0.y,
              t12 = w1.z * s0.z, t13 = w1.w * s0.w;
  orow[32 + 3 * u4] = make_float4(t10 * y.y, t10 * y.z, t10 * y.w, t11 * y.y);
  orow[33 + 3 * u4] = make_float4(t11 * y.z, t11 * y.w, t12 * y.y, t12 * y.z);
  orow[34 + 3 * u4] = make_float4(t12 * y.w, t13 * y.y, t13 * y.z, t13 * y.w);

  // o2[c,i] = w2[c] * s1[c][i] * y0
  const float t20 = w2.x * y.x, t21 = w2.y * y.x,
              t22 = w2.z * y.x, t23 = w2.w * y.x;
  orow[128 + 3 * u4] = make_float4(t20 * sA.x, t20 * sA.y, t20 * sA.z, t21 * sA.w);
  orow[129 + 3 * u4] = make_float4(t21 * sB.x, t21 * sB.y, t22 * sB.z, t22 * sB.w);
  orow[130 + 3 * u4] = make_float4(t22 * sC.x, t23 * sC.y, t23 * sC.z, t23 * sC.w);

  // o3[c] = w3[c] * dot(s1[c], y1) / sqrt(3)
  const float d0 = sA.x * y.y + sA.y * y.z + sA.z * y.w;
  const float d1 = sA.w * y.y + sB.x * y.z + sB.y * y.w;
  const float d2 = sB.z * y.y + sB.w * y.z + sC.x * y.w;
  const float d3 = sC.y * y.y + sC.z * y.z + sC.w * y.w;
  orow[224 + u4] = make_float4(w3.x * d0 * INV_SQRT3, w3.y * d1 * INV_SQRT3,
                               w3.z * d2 * INV_SQRT3, w3.w * d3 * INV_SQRT3);

  // o4[c,k] = w4[c] * cross(s1[c], y1)[k] / sqrt(2)
  const float k40 = w4.x * INV_SQRT2, k41 = w4.y * INV_SQRT2,
              k42 = w4.z * INV_SQRT2, k43 = w4.w * INV_SQRT2;
  // ch0 = (sA.x, sA.y, sA.z); ch1 = (sA.w, sB.x, sB.y);
  // ch2 = (sB.z, sB.w, sC.x); ch3 = (sC.y, sC.z, sC.w)
  const float c0x = sA.y * y.w - sA.z * y.z;
  const float c0y = sA.z * y.y - sA.x * y.w;
  const float c0z = sA.x * y.z - sA.y * y.y;
  const float c1x = sB.x * y.w - sB.y * y.z;
  const float c1y = sB.y * y.y - sA.w * y.w;
  const float c1z = sA.w * y.z - sB.x * y.y;
  const float c2x = sB.w * y.w - sC.x * y.z;
  const float c2y = sC.x * y.y - sB.z * y.w;
  const float c2z = sB.z * y.z - sB.w * y.y;
  const float c3x = sC.z * y.w - sC.w * y.z;
  const float c3y = sC.w * y.y - sC.y * y.w;
  const float c3z = sC.y * y.z - sC.z * y.y;
  orow[256 + 3 * u4] = make_float4(k40 * c0x, k40 * c0y, k40 * c0z, k41 * c1x);
  orow[257 + 3 * u4] = make_float4(k41 * c1y, k41 * c1z, k42 * c2x, k42 * c2y);
  orow[258 + 3 * u4] = make_float4(k42 * c2z, k43 * c3x, k43 * c3y, k43 * c3z);
}

}  // namespace

extern "C" void kernel_launch(void* const* d_in, const int* in_sizes, int n_in,
                              void* d_out, int out_size, void* d_ws, size_t ws_size,
                              hipStream_t stream) {
  const float* x1 = (const float*)d_in[0];
  const float* x2 = (const float*)d_in[1];
  const float* w  = (const float*)d_in[2];
  float* out = (float*)d_out;

  const int nrows = in_sizes[0] / (4 * U);       // B
  const int total = nrows * 32;                  // one thread per (b, 4-channel group)
  const int block = 256;
  const int grid = (total + block - 1) / block;

  hipLaunchKernelGGL(tp_kernel, dim3(grid), dim3(block), 0, stream,
                     x1, x2, w, out, nrows);
}